// Round 17
// baseline (97.804 us; speedup 1.0000x reference)
//
#include <hip/hip_runtime.h>

#define NN 100000
#define NE 3200000
#define NQ (NE / 4)            // 800000 int4 quads

// ---- bucketed-scatter plan constants (R12-proven geometry) ----
#define NCHUNK 32
#define CHUNK 3125             // 32 * 3125 = 100000 exactly; 12.5 KB LDS
#define NBB 512                // bucket blocks
#define BCAP 320               // per-(chunk,block) capacity: mean 195 + 9 sigma
#define NSLICE 16              // scatter slices
#define GPS (NBB / NSLICE)     // segments per scatter slice = 32
#define QPSEG (BCAP / 4)       // 80 uint4 quads per segment
#define BLK_QUADS (GPS * BCAP / 4)   // 2560 quads per scatter block
#define TOTQ (NCHUNK * NBB * QPSEG)  // 1,310,720 quads total
#define GTHREADS (TOTQ / 2)          // 655,360 gather threads (2 quads each)

// --------------------------------------------------------------------------
// Bucket (R6/R12-exact): partition edges by dst-chunk into per-(chunk,block)
// segments via LDS atomic counters. Packed: dst_local(12b)<<17 | src(17b).
__global__ __launch_bounds__(1024) void bucket_kernel(
        const int4* __restrict__ src4, const int4* __restrict__ dst4,
        unsigned* __restrict__ bkt, int* __restrict__ counts) {
    __shared__ int cnt[NCHUNK];
    if (threadIdx.x < NCHUNK) cnt[threadIdx.x] = 0;
    __syncthreads();
    const int b = blockIdx.x;
    const int q0 = (int)(((long long)b * NQ) / NBB);
    const int q1 = (int)(((long long)(b + 1) * NQ) / NBB);
    for (int q = q0 + threadIdx.x; q < q1; q += 1024) {
        const int4 d = dst4[q];
        const int4 s = src4[q];
        const int dd[4] = {d.x, d.y, d.z, d.w};
        const int ss[4] = {s.x, s.y, s.z, s.w};
#pragma unroll
        for (int j = 0; j < 4; ++j) {
            const int c = dd[j] / CHUNK;                  // magic-mul div
            const int slot = atomicAdd(&cnt[c], 1);
            bkt[((size_t)c * NBB + b) * BCAP + slot] =
                ((unsigned)(dd[j] - c * CHUNK) << 17) | (unsigned)ss[j];
        }
    }
    __syncthreads();
    if (threadIdx.x < NCHUNK)
        counts[threadIdx.x * NBB + b] = cnt[threadIdx.x];
}

// --------------------------------------------------------------------------
// Pure streaming-gather: val[pos] = h[src(meta[pos])] for valid slots.
// No LDS / atomics / barriers; 8 guarded gathers in flight per thread;
// float4 val stores are fully coalesced. This kernel's dur_us directly
// measures the irreducible random-gather cost.
__global__ __launch_bounds__(256) void gather_kernel(
        const float* __restrict__ h,
        const uint4* __restrict__ meta4, const int* __restrict__ counts,
        float4* __restrict__ val4) {
    const int t = blockIdx.x * 256 + threadIdx.x;      // < GTHREADS exactly
    const int qa = t, qb = t + GTHREADS;
    const uint4 ma = meta4[qa];
    const uint4 mb = meta4[qb];
    const int sa = qa / QPSEG, sb = qb / QPSEG;        // magic-mul div
    const int ia = (qa - sa * QPSEG) * 4;
    const int ib = (qb - sb * QPSEG) * 4;
    const int na = counts[sa];
    const int nb = counts[sb];
    float4 va = make_float4(0.f, 0.f, 0.f, 0.f);
    float4 vb = make_float4(0.f, 0.f, 0.f, 0.f);
    if (ia + 0 < na) va.x = h[ma.x & 0x1FFFF];
    if (ia + 1 < na) va.y = h[ma.y & 0x1FFFF];
    if (ia + 2 < na) va.z = h[ma.z & 0x1FFFF];
    if (ia + 3 < na) va.w = h[ma.w & 0x1FFFF];
    if (ib + 0 < nb) vb.x = h[mb.x & 0x1FFFF];
    if (ib + 1 < nb) vb.y = h[mb.y & 0x1FFFF];
    if (ib + 2 < nb) vb.z = h[mb.z & 0x1FFFF];
    if (ib + 3 < nb) vb.w = h[mb.w & 0x1FFFF];
    val4[qa] = va;
    val4[qb] = vb;
}

// --------------------------------------------------------------------------
// Gather-free scatter: block (s,c) streams its 2560 (meta,val) quad pairs
// (contiguous, coalesced), LDS-accumulates valid entries, writes one partial.
__global__ __launch_bounds__(1024) void scatter_val_kernel(
        const uint4* __restrict__ meta4, const float4* __restrict__ val4,
        const int* __restrict__ counts, float* __restrict__ partial) {
    __shared__ float acc[CHUNK];
    __shared__ int cnt_l[GPS];
    const int s = blockIdx.x, c = blockIdx.y;
    for (int i = threadIdx.x; i < CHUNK; i += 1024) acc[i] = 0.0f;
    if (threadIdx.x < GPS)
        cnt_l[threadIdx.x] = counts[c * NBB + s * GPS + threadIdx.x];
    __syncthreads();
    const size_t qbase = (size_t)(c * NBB + s * GPS) * QPSEG;
    const uint4* mp4 = meta4 + qbase;
    const float4* vp4 = val4 + qbase;
    for (int quad = threadIdx.x; quad < BLK_QUADS; quad += 1024) {
        const uint4 e = mp4[quad];
        const float4 v = vp4[quad];
        const int blk = quad / QPSEG;                     // magic-mul div
        const int idx = (quad - blk * QPSEG) * 4;
        const int n = cnt_l[blk];
        if (idx + 0 < n) atomicAdd(&acc[e.x >> 17], v.x);
        if (idx + 1 < n) atomicAdd(&acc[e.y >> 17], v.y);
        if (idx + 2 < n) atomicAdd(&acc[e.z >> 17], v.z);
        if (idx + 3 < n) atomicAdd(&acc[e.w >> 17], v.w);
    }
    __syncthreads();
    float* outp = partial + ((size_t)c * NSLICE + s) * CHUNK;
    for (int i = threadIdx.x; i < CHUNK; i += 1024) outp[i] = acc[i];
}

// agg1 = sum over 16 slice partials; s = sum_j relu(agg1*W1+b1)*W2
__global__ __launch_bounds__(256) void reduce_mlp_kernel(
        const float* __restrict__ partial,
        const float* __restrict__ W1, const float* __restrict__ b1,
        const float* __restrict__ W2,
        float* __restrict__ sout, int n) {
    int i = blockIdx.x * blockDim.x + threadIdx.x;
    if (i >= n) return;
    const int c = i / CHUNK;
    const int idx = i - c * CHUNK;
    const float* base = partial + (size_t)c * NSLICE * CHUNK + idx;
    float a = 0.0f;
#pragma unroll
    for (int s = 0; s < NSLICE; ++s) a += base[(size_t)s * CHUNK];
    float r = 0.0f;
#pragma unroll
    for (int j = 0; j < 16; ++j)
        r = fmaf(fmaxf(fmaf(a, W1[j], b1[j]), 0.0f), W2[j], r);
    sout[i] = r;
}

__global__ __launch_bounds__(256) void reduce_final_kernel(
        const float* __restrict__ partial,
        const float* __restrict__ b2,
        float* __restrict__ out, int n) {
    int i = blockIdx.x * blockDim.x + threadIdx.x;
    if (i >= n) return;
    const int c = i / CHUNK;
    const int idx = i - c * CHUNK;
    const float* base = partial + (size_t)c * NSLICE * CHUNK + idx;
    float a = 0.0f;
#pragma unroll
    for (int s = 0; s < NSLICE; ++s) a += base[(size_t)s * CHUNK];
    out[i] = fmaxf(a + b2[0], 0.0f);
}

// ---------------- Fallback: global-atomic path ------------------------------
__global__ void zero_kernel(float* __restrict__ p, int n) {
    int i = blockIdx.x * blockDim.x + threadIdx.x;
    int st = gridDim.x * blockDim.x;
    for (; i < n; i += st) p[i] = 0.0f;
}
__global__ __launch_bounds__(256) void edge_scatter_kernel(
        const float* __restrict__ h, const int4* __restrict__ src4,
        const int4* __restrict__ dst4, float* __restrict__ agg, int nquad) {
    int i = blockIdx.x * blockDim.x + threadIdx.x;
    if (i >= nquad) return;
    int4 s = src4[i]; int4 d = dst4[i];
    atomicAdd(&agg[d.x], h[s.x]);
    atomicAdd(&agg[d.y], h[s.y]);
    atomicAdd(&agg[d.z], h[s.z]);
    atomicAdd(&agg[d.w], h[s.w]);
}
__global__ __launch_bounds__(256) void mlp_kernel(
        const float* __restrict__ agg1, const float* __restrict__ W1,
        const float* __restrict__ b1, const float* __restrict__ W2,
        float* __restrict__ sout, int n) {
    int i = blockIdx.x * blockDim.x + threadIdx.x;
    if (i >= n) return;
    float a = agg1[i], r = 0.0f;
#pragma unroll
    for (int j = 0; j < 16; ++j)
        r = fmaf(fmaxf(fmaf(a, W1[j], b1[j]), 0.0f), W2[j], r);
    sout[i] = r;
}
__global__ __launch_bounds__(256) void finalize_kernel(
        float* __restrict__ out, const float* __restrict__ b2, int n) {
    int i = blockIdx.x * blockDim.x + threadIdx.x;
    if (i >= n) return;
    out[i] = fmaxf(out[i] + b2[0], 0.0f);
}

extern "C" void kernel_launch(void* const* d_in, const int* in_sizes, int n_in,
                              void* d_out, int out_size, void* d_ws, size_t ws_size,
                              hipStream_t stream) {
    const float* features = (const float*)d_in[0];
    const int*   src      = (const int*)d_in[1];
    const int*   dst      = (const int*)d_in[2];
    const float* W1       = (const float*)d_in[3];
    const float* b1       = (const float*)d_in[4];
    const float* W2       = (const float*)d_in[5];
    const float* b2       = (const float*)d_in[6];
    float* out = (float*)d_out;

    const int4* src4 = (const int4*)src;
    const int4* dst4 = (const int4*)dst;
    const int nb = (NN + 255) / 256;

    // Plan A: bucket + split gather/scatter (~49 MB ws)
    {
        const size_t bkt_elems  = (size_t)NCHUNK * NBB * BCAP;       // 5.24M u32
        const size_t cnt_elems  = (size_t)NCHUNK * NBB;              // 16384 int
        const size_t val_elems  = bkt_elems;                         // 5.24M f32
        const size_t part_elems = (size_t)NCHUNK * NSLICE * CHUNK;   // 1.6M f32
        const size_t need =
            (bkt_elems + cnt_elems + val_elems + part_elems + NN) * 4;
        if (ws_size >= need) {
            unsigned* bkt  = (unsigned*)d_ws;
            int* counts    = (int*)(bkt + bkt_elems);
            float* val     = (float*)(counts + cnt_elems);
            float* partial = val + val_elems;
            float* sbuf    = partial + part_elems;

            const uint4* meta4 = (const uint4*)bkt;
            float4* val4 = (float4*)val;

            bucket_kernel<<<NBB, 1024, 0, stream>>>(src4, dst4, bkt, counts);
            dim3 g(NSLICE, NCHUNK);

            gather_kernel<<<GTHREADS / 256, 256, 0, stream>>>(
                features, meta4, counts, val4);
            scatter_val_kernel<<<g, 1024, 0, stream>>>(
                meta4, (const float4*)val4, counts, partial);
            reduce_mlp_kernel<<<nb, 256, 0, stream>>>(partial, W1, b1, W2, sbuf, NN);

            gather_kernel<<<GTHREADS / 256, 256, 0, stream>>>(
                sbuf, meta4, counts, val4);
            scatter_val_kernel<<<g, 1024, 0, stream>>>(
                meta4, (const float4*)val4, counts, partial);
            reduce_final_kernel<<<nb, 256, 0, stream>>>(partial, b2, out, NN);
            return;
        }
    }
    // Fallback: global atomics
    {
        float* agg1 = (float*)d_ws;
        float* sbuf = agg1 + NN;
        const int eb = (NQ + 255) / 256;
        zero_kernel<<<256, 256, 0, stream>>>(agg1, NN);
        edge_scatter_kernel<<<eb, 256, 0, stream>>>(features, src4, dst4, agg1, NQ);
        mlp_kernel<<<nb, 256, 0, stream>>>(agg1, W1, b1, W2, sbuf, NN);
        zero_kernel<<<256, 256, 0, stream>>>(out, NN);
        edge_scatter_kernel<<<eb, 256, 0, stream>>>(sbuf, src4, dst4, out, NQ);
        finalize_kernel<<<nb, 256, 0, stream>>>(out, b2, NN);
    }
}

// Round 18
// 63.771 us; speedup vs baseline: 1.5337x; 1.5337x over previous
//
#include <hip/hip_runtime.h>

#define NN 100000
#define NE 3200000
#define NQ (NE / 4)            // 800000 int4 quads

// ---- bucketed-scatter plan constants (R6/R12-proven geometry) ----
#define NCHUNK 32
#define CHUNK 3125             // 32 * 3125 = 100000 exactly; 12.5 KB LDS
#define NBB 512                // bucket blocks
#define BCAP 320               // per-(chunk,block) capacity: mean 195 + 9 sigma
#define NSLICE 16              // scatter slices
#define GPS (NBB / NSLICE)     // segments per scatter slice = 32
#define QPSEG (BCAP / 4)       // 80 uint4 quads per segment
#define BLK_QUADS (GPS * BCAP / 4)   // 2560 quads per scatter block

// --------------------------------------------------------------------------
// Bucket: partition edges by dst-chunk into per-(chunk,block) segments via
// LDS atomic counters. Packed: dst_local(12b)<<17 | src(17b).
__global__ __launch_bounds__(1024) void bucket_kernel(
        const int4* __restrict__ src4, const int4* __restrict__ dst4,
        unsigned* __restrict__ bkt, int* __restrict__ counts) {
    __shared__ int cnt[NCHUNK];
    if (threadIdx.x < NCHUNK) cnt[threadIdx.x] = 0;
    __syncthreads();
    const int b = blockIdx.x;
    const int q0 = (int)(((long long)b * NQ) / NBB);
    const int q1 = (int)(((long long)(b + 1) * NQ) / NBB);
    for (int q = q0 + threadIdx.x; q < q1; q += 1024) {
        const int4 d = dst4[q];
        const int4 s = src4[q];
        const int dd[4] = {d.x, d.y, d.z, d.w};
        const int ss[4] = {s.x, s.y, s.z, s.w};
#pragma unroll
        for (int j = 0; j < 4; ++j) {
            const int c = dd[j] / CHUNK;                  // magic-mul div
            const int slot = atomicAdd(&cnt[c], 1);
            bkt[((size_t)c * NBB + b) * BCAP + slot] =
                ((unsigned)(dd[j] - c * CHUNK) << 17) | (unsigned)ss[j];
        }
    }
    __syncthreads();
    if (threadIdx.x < NCHUNK)
        counts[threadIdx.x * NBB + b] = cnt[threadIdx.x];
}

// --------------------------------------------------------------------------
// Scatter (R12 champion form): block (s,c) streams its 32 contiguous
// segments block-wide as coalesced uint4, validity = idx < cnt[blk],
// LDS-accumulates into the 12.5 KB chunk acc, writes one dense partial.
__global__ __launch_bounds__(1024) void scatter_bkt_kernel(
        const float* __restrict__ h,
        const unsigned* __restrict__ bkt, const int* __restrict__ counts,
        float* __restrict__ partial) {
    __shared__ float acc[CHUNK];
    __shared__ int cnt_l[GPS];
    const int s = blockIdx.x, c = blockIdx.y;
    for (int i = threadIdx.x; i < CHUNK; i += 1024) acc[i] = 0.0f;
    if (threadIdx.x < GPS)
        cnt_l[threadIdx.x] = counts[c * NBB + s * GPS + threadIdx.x];
    __syncthreads();
    const uint4* mp4 =
        (const uint4*)(bkt + ((size_t)c * NBB + s * GPS) * BCAP);
#pragma unroll
    for (int k = 0; k < BLK_QUADS / 1024; ++k) {          // 2 full rounds
        const int quad = k * 1024 + threadIdx.x;
        const uint4 e = mp4[quad];
        const int blk = quad / QPSEG;                     // magic-mul div
        const int idx = (quad - blk * QPSEG) * 4;
        const int n = cnt_l[blk];
        if (idx + 0 < n) atomicAdd(&acc[e.x >> 17], h[e.x & 0x1FFFF]);
        if (idx + 1 < n) atomicAdd(&acc[e.y >> 17], h[e.y & 0x1FFFF]);
        if (idx + 2 < n) atomicAdd(&acc[e.z >> 17], h[e.z & 0x1FFFF]);
        if (idx + 3 < n) atomicAdd(&acc[e.w >> 17], h[e.w & 0x1FFFF]);
    }
    {   // remainder: quads 2048..2559
        const int quad = 2 * 1024 + threadIdx.x;
        if (quad < BLK_QUADS) {
            const uint4 e = mp4[quad];
            const int blk = quad / QPSEG;
            const int idx = (quad - blk * QPSEG) * 4;
            const int n = cnt_l[blk];
            if (idx + 0 < n) atomicAdd(&acc[e.x >> 17], h[e.x & 0x1FFFF]);
            if (idx + 1 < n) atomicAdd(&acc[e.y >> 17], h[e.y & 0x1FFFF]);
            if (idx + 2 < n) atomicAdd(&acc[e.z >> 17], h[e.z & 0x1FFFF]);
            if (idx + 3 < n) atomicAdd(&acc[e.w >> 17], h[e.w & 0x1FFFF]);
        }
    }
    __syncthreads();
    float* outp = partial + ((size_t)c * NSLICE + s) * CHUNK;
    for (int i = threadIdx.x; i < CHUNK; i += 1024) outp[i] = acc[i];
}

// agg1 = sum over 16 slice partials; s = sum_j relu(agg1*W1+b1)*W2
__global__ __launch_bounds__(256) void reduce_mlp_kernel(
        const float* __restrict__ partial,
        const float* __restrict__ W1, const float* __restrict__ b1,
        const float* __restrict__ W2,
        float* __restrict__ sout, int n) {
    int i = blockIdx.x * blockDim.x + threadIdx.x;
    if (i >= n) return;
    const int c = i / CHUNK;
    const int idx = i - c * CHUNK;
    const float* base = partial + (size_t)c * NSLICE * CHUNK + idx;
    float a = 0.0f;
#pragma unroll
    for (int s = 0; s < NSLICE; ++s) a += base[(size_t)s * CHUNK];
    float r = 0.0f;
#pragma unroll
    for (int j = 0; j < 16; ++j)
        r = fmaf(fmaxf(fmaf(a, W1[j], b1[j]), 0.0f), W2[j], r);
    sout[i] = r;
}

__global__ __launch_bounds__(256) void reduce_final_kernel(
        const float* __restrict__ partial,
        const float* __restrict__ b2,
        float* __restrict__ out, int n) {
    int i = blockIdx.x * blockDim.x + threadIdx.x;
    if (i >= n) return;
    const int c = i / CHUNK;
    const int idx = i - c * CHUNK;
    const float* base = partial + (size_t)c * NSLICE * CHUNK + idx;
    float a = 0.0f;
#pragma unroll
    for (int s = 0; s < NSLICE; ++s) a += base[(size_t)s * CHUNK];
    out[i] = fmaxf(a + b2[0], 0.0f);
}

// ---------------- Fallback: global-atomic path ------------------------------
__global__ void zero_kernel(float* __restrict__ p, int n) {
    int i = blockIdx.x * blockDim.x + threadIdx.x;
    int st = gridDim.x * blockDim.x;
    for (; i < n; i += st) p[i] = 0.0f;
}
__global__ __launch_bounds__(256) void edge_scatter_kernel(
        const float* __restrict__ h, const int4* __restrict__ src4,
        const int4* __restrict__ dst4, float* __restrict__ agg, int nquad) {
    int i = blockIdx.x * blockDim.x + threadIdx.x;
    if (i >= nquad) return;
    int4 s = src4[i]; int4 d = dst4[i];
    atomicAdd(&agg[d.x], h[s.x]);
    atomicAdd(&agg[d.y], h[s.y]);
    atomicAdd(&agg[d.z], h[s.z]);
    atomicAdd(&agg[d.w], h[s.w]);
}
__global__ __launch_bounds__(256) void mlp_kernel(
        const float* __restrict__ agg1, const float* __restrict__ W1,
        const float* __restrict__ b1, const float* __restrict__ W2,
        float* __restrict__ sout, int n) {
    int i = blockIdx.x * blockDim.x + threadIdx.x;
    if (i >= n) return;
    float a = agg1[i], r = 0.0f;
#pragma unroll
    for (int j = 0; j < 16; ++j)
        r = fmaf(fmaxf(fmaf(a, W1[j], b1[j]), 0.0f), W2[j], r);
    sout[i] = r;
}
__global__ __launch_bounds__(256) void finalize_kernel(
        float* __restrict__ out, const float* __restrict__ b2, int n) {
    int i = blockIdx.x * blockDim.x + threadIdx.x;
    if (i >= n) return;
    out[i] = fmaxf(out[i] + b2[0], 0.0f);
}

extern "C" void kernel_launch(void* const* d_in, const int* in_sizes, int n_in,
                              void* d_out, int out_size, void* d_ws, size_t ws_size,
                              hipStream_t stream) {
    const float* features = (const float*)d_in[0];
    const int*   src      = (const int*)d_in[1];
    const int*   dst      = (const int*)d_in[2];
    const float* W1       = (const float*)d_in[3];
    const float* b1       = (const float*)d_in[4];
    const float* W2       = (const float*)d_in[5];
    const float* b2       = (const float*)d_in[6];
    float* out = (float*)d_out;

    const int4* src4 = (const int4*)src;
    const int4* dst4 = (const int4*)dst;
    const int nb = (NN + 255) / 256;

    // Plan A: bucketed scatter, dense-streaming scatter loop (~28 MB ws)
    {
        const size_t bkt_elems  = (size_t)NCHUNK * NBB * BCAP;       // 5.24M u32
        const size_t cnt_elems  = (size_t)NCHUNK * NBB;              // 16384 int
        const size_t part_elems = (size_t)NCHUNK * NSLICE * CHUNK;   // 1.6M f32
        const size_t need = (bkt_elems + cnt_elems + part_elems + NN) * 4;
        if (ws_size >= need) {
            unsigned* bkt  = (unsigned*)d_ws;
            int* counts    = (int*)(bkt + bkt_elems);
            float* partial = (float*)(counts + cnt_elems);
            float* sbuf    = partial + part_elems;

            bucket_kernel<<<NBB, 1024, 0, stream>>>(src4, dst4, bkt, counts);
            dim3 g(NSLICE, NCHUNK);
            scatter_bkt_kernel<<<g, 1024, 0, stream>>>(features, bkt, counts, partial);
            reduce_mlp_kernel<<<nb, 256, 0, stream>>>(partial, W1, b1, W2, sbuf, NN);
            scatter_bkt_kernel<<<g, 1024, 0, stream>>>(sbuf, bkt, counts, partial);
            reduce_final_kernel<<<nb, 256, 0, stream>>>(partial, b2, out, NN);
            return;
        }
    }
    // Fallback: global atomics
    {
        float* agg1 = (float*)d_ws;
        float* sbuf = agg1 + NN;
        const int eb = (NQ + 255) / 256;
        zero_kernel<<<256, 256, 0, stream>>>(agg1, NN);
        edge_scatter_kernel<<<eb, 256, 0, stream>>>(features, src4, dst4, agg1, NQ);
        mlp_kernel<<<nb, 256, 0, stream>>>(agg1, W1, b1, W2, sbuf, NN);
        zero_kernel<<<256, 256, 0, stream>>>(out, NN);
        edge_scatter_kernel<<<eb, 256, 0, stream>>>(sbuf, src4, dst4, out, NQ);
        finalize_kernel<<<nb, 256, 0, stream>>>(out, b2, NN);
    }
}